// Round 7
// baseline (589.987 us; speedup 1.0000x reference)
//
#include <hip/hip_runtime.h>
#include <hip/hip_fp8.h>

#define NN 6144
#define F1 128
#define KSPLIT 8
#define KC 768
#define SSCALE 512.0f
#define SSCALE_INV (1.0f / 512.0f)

typedef __attribute__((ext_vector_type(4))) float f32x4;

// pack 4 floats -> 4 fp8 e4m3 bytes (little-endian order a,b,c,d)
__device__ __forceinline__ unsigned int pack4_fp8(float a, float b, float c, float d) {
#if __has_builtin(__builtin_amdgcn_cvt_pk_fp8_f32)
  int v = __builtin_amdgcn_cvt_pk_fp8_f32(a, b, 0, false);
  v = __builtin_amdgcn_cvt_pk_fp8_f32(c, d, v, true);
  return (unsigned int)v;
#else
  __hip_fp8_e4m3 qa(a), qb(b), qc(c), qd(d);
  return (unsigned)qa.__x | ((unsigned)qb.__x << 8) | ((unsigned)qc.__x << 16) |
         ((unsigned)qd.__x << 24);
#endif
}

__device__ __forceinline__ unsigned char f2fp8(float a) {
#if __has_builtin(__builtin_amdgcn_cvt_pk_fp8_f32)
  return (unsigned char)(__builtin_amdgcn_cvt_pk_fp8_f32(a, a, 0, false) & 0xFF);
#else
  __hip_fp8_e4m3 q(a);
  return q.__x;
#endif
}

// ---------------------------------------------------------------- prep
__global__ __launch_bounds__(128) void prep_kernel(
    const float* __restrict__ x5, const float* __restrict__ x0,
    const float* __restrict__ W_gat, const float* __restrict__ b_gat,
    const float* __restrict__ W_lin, const float* __restrict__ b_lin,
    float* __restrict__ hT, float* __restrict__ sq,
    float* __restrict__ Tx0, unsigned char* __restrict__ XT0) {
  int i = blockIdx.x;
  int t = threadIdx.x;
  __shared__ float xs[64];
  __shared__ float x5s[3];
  __shared__ float hs[6];
  if (t < 3) x5s[t] = x5[i * 3 + t];
  if (t < 64) xs[t] = x0[(size_t)i * 64 + t];
  __syncthreads();
  if (t < 6) {
    float a = b_gat[t];
#pragma unroll
    for (int k = 0; k < 3; k++) a += x5s[k] * W_gat[k * 6 + t];
    a = fmaxf(a, 0.f);
    hs[t] = a;
    hT[(size_t)t * NN + i] = a;
  }
  __syncthreads();
  if (t == 0) {
    float s = 0.f;
#pragma unroll
    for (int k = 0; k < 6; k++) s += hs[k] * hs[k];
    sq[i] = s;
  }
  float a = b_lin[t];
#pragma unroll 16
  for (int k = 0; k < 64; k++) a += xs[k] * W_lin[k * 128 + t];
  a = fmaxf(a, 0.f);
  Tx0[(size_t)i * F1 + t] = a;
  XT0[(size_t)t * NN + i] = f2fp8(a);
}

// ---------------------------------------------------------------- prob
__global__ __launch_bounds__(256) void prob_kernel(
    const float* __restrict__ hT, const float* __restrict__ sq,
    float* __restrict__ P, float* __restrict__ dinv) {
  int i = blockIdx.x;
  int t = threadIdx.x;
  float h0 = hT[i], h1 = hT[NN + i], h2 = hT[2 * NN + i];
  float h3 = hT[3 * NN + i], h4 = hT[4 * NN + i], h5 = hT[5 * NN + i];
  float si = sq[i];
  float acc = 0.f;
  float* Pr = P + (size_t)i * NN;
  for (int j = t; j < NN; j += 256) {
    float dot = h0 * hT[j] + h1 * hT[NN + j] + h2 * hT[2 * NN + j] +
                h3 * hT[3 * NN + j] + h4 * hT[4 * NN + j] + h5 * hT[5 * NN + j];
    float d = si + sq[j] - 2.f * dot;
    float p = __expf(-0.5f * d);
    Pr[j] = p;
    if (j != i) acc += p;
  }
  __shared__ float red[256];
  red[t] = acc;
  __syncthreads();
  for (int s = 128; s > 0; s >>= 1) {
    if (t < s) red[t] += red[t + s];
    __syncthreads();
  }
  if (t == 0) {
    float deg = red[0];
    dinv[i] = deg > 0.f ? rsqrtf(deg) : 0.f;
  }
}

// ---------------------------------------------------------------- smat (fp8, scaled by 512)
__global__ __launch_bounds__(256) void smat_kernel(
    const float* __restrict__ hT, const float* __restrict__ sq,
    const float* __restrict__ dinv, unsigned int* __restrict__ S32) {
  int i = blockIdx.x;
  int t = threadIdx.x;
  float h0 = hT[i], h1 = hT[NN + i], h2 = hT[2 * NN + i];
  float h3 = hT[3 * NN + i], h4 = hT[4 * NN + i], h5 = hT[5 * NN + i];
  float si = sq[i];
  float dis = -SSCALE * dinv[i];
  unsigned int* Sr = S32 + (size_t)i * (NN / 4);
  for (int j4 = t; j4 < NN / 4; j4 += 256) {
    int j = j4 * 4;
    float4 qv = *(const float4*)(sq + j);
    float4 dj = *(const float4*)(dinv + j);
    float4 v0 = *(const float4*)(hT + j);
    float4 v1 = *(const float4*)(hT + NN + j);
    float4 v2 = *(const float4*)(hT + 2 * NN + j);
    float4 v3 = *(const float4*)(hT + 3 * NN + j);
    float4 v4 = *(const float4*)(hT + 4 * NN + j);
    float4 v5 = *(const float4*)(hT + 5 * NN + j);
    float s[4];
#pragma unroll
    for (int m = 0; m < 4; m++) {
      float dot = h0 * ((const float*)&v0)[m] + h1 * ((const float*)&v1)[m] +
                  h2 * ((const float*)&v2)[m] + h3 * ((const float*)&v3)[m] +
                  h4 * ((const float*)&v4)[m] + h5 * ((const float*)&v5)[m];
      float d = si + ((const float*)&qv)[m] - 2.f * dot;
      float p = __expf(-0.5f * d);
      s[m] = dis * p * ((const float*)&dj)[m];
      if (j + m == i) s[m] = 0.f;
    }
    Sr[j4] = pack4_fp8(s[0], s[1], s[2], s[3]);
  }
}

// ---------------------------------------------------------------- gemm (fp8, split-K partials)
// grid 768 = (96 mb x 8 ks), block 128 (2 waves); wave = 32 rows x 128 cols.
// 1536 waves (~1.5/SIMD). A-traffic 37.7 MB/gemm (fp8), B (0.79 MB) L2-resident.
__global__ __launch_bounds__(128, 3) void gemm_kernel(
    const unsigned char* __restrict__ S, const unsigned char* __restrict__ XT,
    float* __restrict__ partial) {
  // bijective XCD swizzle: 768 = 8 XCDs x 96; each XCD gets all mb of one ks
  int orig = blockIdx.x;
  int wgid = (orig & 7) * 96 + (orig >> 3);
  int mb = wgid % 96;
  int ks = wgid / 96;
  int w = threadIdx.x >> 6;
  int l = threadIdx.x & 63;
  int lr = l & 15;
  int lg = l >> 4;
  int row0 = mb * 64 + w * 32;
  int k0 = ks * KC;

  f32x4 acc[2][8];
#pragma unroll
  for (int rb = 0; rb < 2; rb++)
#pragma unroll
    for (int n = 0; n < 8; n++) acc[rb][n] = (f32x4){0.f, 0.f, 0.f, 0.f};

  const unsigned char* Ab = S + (size_t)(row0 + lr) * NN + k0 + lg * 8;
  const unsigned char* Bb = XT + (size_t)lr * NN + k0 + lg * 8;

#pragma unroll 3
  for (int kk = 0; kk < KC; kk += 32) {
    long a0 = *(const long*)(Ab + kk);
    long a1 = *(const long*)(Ab + (size_t)16 * NN + kk);
#pragma unroll
    for (int n = 0; n < 8; n++) {
      long b = *(const long*)(Bb + (size_t)n * 16 * NN + kk);
      acc[0][n] = __builtin_amdgcn_mfma_f32_16x16x32_fp8_fp8(a0, b, acc[0][n], 0, 0, 0);
      acc[1][n] = __builtin_amdgcn_mfma_f32_16x16x32_fp8_fp8(a1, b, acc[1][n], 0, 0, 0);
    }
  }

  // C/D layout: col = lane&15, row-in-16 = lg*4 + r
  float* pbase = partial + (size_t)ks * NN * F1;
#pragma unroll
  for (int rb = 0; rb < 2; rb++) {
    int rowo = row0 + rb * 16 + lg * 4;
#pragma unroll
    for (int n = 0; n < 8; n++) {
#pragma unroll
      for (int r = 0; r < 4; r++) {
        pbase[(size_t)(rowo + r) * F1 + n * 16 + lr] = acc[rb][n][r];
      }
    }
  }
}

// ---------------------------------------------------------------- finalize
// thread: rquad = t>>5 (4 consecutive rows), c4 = t&31 (4 features).
// Coalesced partial reads; XT written as packed uint (4 rows of one feature).
__global__ __launch_bounds__(256) void finalize_kernel(
    const float4* __restrict__ partial, const float4* __restrict__ prevprev,
    float4* __restrict__ TxOut, unsigned int* __restrict__ XT8, int dsub) {
  const int TOT4 = NN * F1 / 4;
  int t = threadIdx.x;
  int rquad = t >> 5, c4 = t & 31;
  int row0 = blockIdx.x * 32 + rquad * 4;
  float g[4][4];
#pragma unroll
  for (int rr = 0; rr < 4; rr++) {
    int fidx = (row0 + rr) * 32 + c4;
    float4 a = partial[fidx];
#pragma unroll
    for (int s = 1; s < KSPLIT; s++) {
      float4 p = partial[(size_t)s * TOT4 + fidx];
      a.x += p.x; a.y += p.y; a.z += p.z; a.w += p.w;
    }
    a.x *= SSCALE_INV; a.y *= SSCALE_INV; a.z *= SSCALE_INV; a.w *= SSCALE_INV;
    if (dsub) {
      float4 q = prevprev[fidx];
      a.x = 2.f * a.x - q.x; a.y = 2.f * a.y - q.y;
      a.z = 2.f * a.z - q.z; a.w = 2.f * a.w - q.w;
    }
    TxOut[fidx] = a;
    g[rr][0] = a.x; g[rr][1] = a.y; g[rr][2] = a.z; g[rr][3] = a.w;
  }
#pragma unroll
  for (int j = 0; j < 4; j++) {
    unsigned int pk = pack4_fp8(g[0][j], g[1][j], g[2][j], g[3][j]);
    XT8[(((size_t)(c4 * 4 + j)) * NN + row0) >> 2] = pk;
  }
}

// ---------------------------------------------------------------- epilogue
__global__ __launch_bounds__(256) void out_kernel(
    const float* __restrict__ Tx, const float* __restrict__ Wcat,
    const float* __restrict__ b3, const float* __restrict__ b6,
    const float* __restrict__ b9,
    const float* __restrict__ Wl, const float* __restrict__ bl,
    float* __restrict__ x_out, float* __restrict__ last_out) {
  __shared__ float WS[128 * 48];
  __shared__ float TxS[32][129];
  __shared__ float lo[32][48];
  __shared__ float lg[32][16];
  __shared__ float le[32][16];
  __shared__ float WlS[48 * 16];
  __shared__ float blS[16];
  int t = threadIdx.x;
  int row0 = blockIdx.x * 32;
  int rg = t >> 4;
  int cg = t & 15;
  float acc[2][3] = {{0.f, 0.f, 0.f}, {0.f, 0.f, 0.f}};
  for (int i = t; i < 768; i += 256) WlS[i] = Wl[i];
  if (t < 16) blS[t] = bl[t];
  for (int k = 0; k < 9; k++) {
    for (int i = t; i < 6144; i += 256) WS[i] = Wcat[k * 6144 + i];
    for (int i = t; i < 4096; i += 256) {
      int r = i >> 7, j = i & 127;
      TxS[r][j] = Tx[((size_t)k * NN + row0 + r) * F1 + j];
    }
    __syncthreads();
#pragma unroll 4
    for (int j = 0; j < 128; j++) {
      float t0 = TxS[2 * rg][j], t1 = TxS[2 * rg + 1][j];
      const float* wp = &WS[j * 48 + 3 * cg];
      float w0 = wp[0], w1 = wp[1], w2 = wp[2];
      acc[0][0] += t0 * w0; acc[0][1] += t0 * w1; acc[0][2] += t0 * w2;
      acc[1][0] += t1 * w0; acc[1][1] += t1 * w1; acc[1][2] += t1 * w2;
    }
    __syncthreads();
  }
#pragma unroll
  for (int rr = 0; rr < 2; rr++) {
    int r = 2 * rg + rr;
#pragma unroll
    for (int cc = 0; cc < 3; cc++) {
      int c = 3 * cg + cc;
      float bias = c < 16 ? b3[c] : (c < 32 ? b6[c - 16] : b9[c - 32]);
      float v = acc[rr][cc] + bias;
      lo[r][c] = v;
      last_out[(size_t)(row0 + r) * 48 + c] = v;
    }
  }
  __syncthreads();
#pragma unroll
  for (int s = 0; s < 2; s++) {
    int idx = t + 256 * s;
    int r = idx >> 4, c = idx & 15;
    float lgt = blS[c];
#pragma unroll 8
    for (int j = 0; j < 48; j++) lgt += lo[r][j] * WlS[j * 16 + c];
    lg[r][c] = lgt;
  }
  __syncthreads();
#pragma unroll
  for (int s = 0; s < 2; s++) {
    int idx = t + 256 * s;
    int r = idx >> 4, c = idx & 15;
    float mx = lg[r][0];
#pragma unroll
    for (int j = 1; j < 16; j++) mx = fmaxf(mx, lg[r][j]);
    le[r][c] = __expf(lg[r][c] - mx);
  }
  __syncthreads();
#pragma unroll
  for (int s = 0; s < 2; s++) {
    int idx = t + 256 * s;
    int r = idx >> 4, c = idx & 15;
    float sum = 0.f;
#pragma unroll
    for (int j = 0; j < 16; j++) sum += le[r][j];
    x_out[(size_t)(row0 + r) * 16 + c] = le[r][c] / sum;
  }
}

// ---------------------------------------------------------------- misc copies + Wcat build
__global__ __launch_bounds__(256) void copy_kernel(
    const int* __restrict__ tr, const int* __restrict__ val,
    const float* __restrict__ x0, float* __restrict__ tr_out,
    float* __restrict__ val_out, float* __restrict__ x0_out,
    const float* __restrict__ W3, const float* __restrict__ W6,
    const float* __restrict__ W9, float* __restrict__ Wcat) {
  int i = blockIdx.x * 256 + threadIdx.x;
  if (i < 4000) tr_out[i] = (float)tr[i];
  if (i < 1000) val_out[i] = (float)val[i];
  if (i < NN * 64) x0_out[i] = x0[i];
  if (i < 9 * 128 * 48) {
    int c = i % 48;
    int j = (i / 48) % 128;
    int k = i / (48 * 128);
    float v = 0.f;
    if (c < 16) {
      if (k < 3) v = W3[(k * 128 + j) * 16 + c];
    } else if (c < 32) {
      if (k < 6) v = W6[(k * 128 + j) * 16 + (c - 16)];
    } else {
      v = W9[(k * 128 + j) * 16 + (c - 32)];
    }
    Wcat[i] = v;
  }
}

extern "C" void kernel_launch(void* const* d_in, const int* in_sizes, int n_in,
                              void* d_out, int out_size, void* d_ws, size_t ws_size,
                              hipStream_t stream) {
  const float* x5 = (const float*)d_in[0];
  const float* x0 = (const float*)d_in[1];
  const int* tr = (const int*)d_in[2];
  const int* val = (const int*)d_in[3];
  const float* W_gat = (const float*)d_in[4];
  const float* b_gat = (const float*)d_in[5];
  const float* W_lin = (const float*)d_in[6];
  const float* b_lin = (const float*)d_in[7];
  const float* W3 = (const float*)d_in[8];
  const float* b3 = (const float*)d_in[9];
  const float* W6 = (const float*)d_in[10];
  const float* b6 = (const float*)d_in[11];
  const float* W9 = (const float*)d_in[12];
  const float* b9 = (const float*)d_in[13];
  const float* Wl = (const float*)d_in[14];
  const float* bl = (const float*)d_in[15];

  float* out = (float*)d_out;
  float* x_out = out;
  float* tr_out = x_out + (size_t)NN * 16;
  float* val_out = tr_out + 4000;
  float* P = val_out + 1000;
  float* last_out = P + (size_t)NN * NN;
  float* x0_out = last_out + (size_t)NN * 48;

  char* w = (char*)d_ws;
  unsigned char* Sb = (unsigned char*)w;    w += (size_t)NN * NN;
  float* Tx = (float*)w;                    w += (size_t)9 * NN * F1 * 4;
  float* partial = (float*)w;               w += (size_t)KSPLIT * NN * F1 * 4;
  unsigned char* XTa = (unsigned char*)w;   w += (size_t)NN * F1;
  unsigned char* XTb = (unsigned char*)w;   w += (size_t)NN * F1;
  float* hT = (float*)w;                    w += (size_t)6 * NN * 4;
  float* sq = (float*)w;                    w += (size_t)NN * 4;
  float* dinv = (float*)w;                  w += (size_t)NN * 4;
  float* Wcat = (float*)w;                  w += (size_t)9 * 128 * 48 * 4;

  prep_kernel<<<NN, 128, 0, stream>>>(x5, x0, W_gat, b_gat, W_lin, b_lin, hT, sq,
                                      Tx, XTa);
  prob_kernel<<<NN, 256, 0, stream>>>(hT, sq, P, dinv);
  smat_kernel<<<NN, 256, 0, stream>>>(hT, sq, dinv, (unsigned int*)Sb);
  copy_kernel<<<1536, 256, 0, stream>>>(tr, val, x0, tr_out, val_out, x0_out,
                                        W3, W6, W9, Wcat);

  unsigned char* xin = XTa;
  unsigned char* xout = XTb;
  for (int k = 1; k <= 8; k++) {
    gemm_kernel<<<768, 128, 0, stream>>>(Sb, xin, partial);
    const float4* pp = (const float4*)(Tx + (size_t)(k >= 2 ? k - 2 : 0) * NN * F1);
    finalize_kernel<<<192, 256, 0, stream>>>((const float4*)partial, pp,
                                             (float4*)(Tx + (size_t)k * NN * F1),
                                             (unsigned int*)xout, k >= 2 ? 1 : 0);
    unsigned char* tmp = xin; xin = xout; xout = tmp;
  }

  out_kernel<<<192, 256, 0, stream>>>(Tx, Wcat, b3, b6, b9, Wl, bl, x_out,
                                      last_out);
}